// Round 6
// baseline (672.834 us; speedup 1.0000x reference)
//
#include <hip/hip_runtime.h>

// Problem constants: B=1, T=5, C=64, H=W=32, F=10
#define N_TOK   5120      // T*H*W
#define C_IN    64
#define F_OUT   10
#define FP      12        // padded row stride: [0..9]=data, [10]=invw (K only)

#define DTILE   40        // denom: Q rows staged per LDS tile
#define MTILE   40        // main: K/V rows staged per LDS tile
#define GRID    640       // launch_bounds(256,3) => >=3 blk/CU => 768 capacity >= 640

// ---------------------------------------------------------------------------
// Manual grid barrier. Counters zeroed by hipMemsetAsync before the kernel.
// Agent-scope atomics + __threadfence() handle cross-XCD L2 non-coherence.
// Spin bails out after ~1e8 polls: a bug degrades to wrong answer, not a hang.
// ---------------------------------------------------------------------------
__device__ __forceinline__ void grid_barrier(unsigned* __restrict__ bar,
                                             int idx, unsigned target)
{
    __syncthreads();                 // all block stores issued (+vmcnt drained)
    if (threadIdx.x == 0) {
        __threadfence();             // release: flush this XCD's L2 writes
        __hip_atomic_fetch_add(&bar[idx * 16], 1u, __ATOMIC_RELEASE,
                               __HIP_MEMORY_SCOPE_AGENT);
        unsigned spins = 0;
        while (__hip_atomic_load(&bar[idx * 16], __ATOMIC_ACQUIRE,
                                 __HIP_MEMORY_SCOPE_AGENT) < target) {
            __builtin_amdgcn_s_sleep(8);
            if (++spins > 100000000u) break;
        }
    }
    __syncthreads();
    __threadfence();                 // acquire: invalidate stale cached lines
}

// ---------------------------------------------------------------------------
// Single fused kernel: 5 phases separated by manual grid barriers.
//  P1 qkv     : 600 units -> Q/K/V [N][FP]
//  P2 denom   : 5*NCH units -> dpart[nc][m]
//  P3 invw    : 20 units -> K[m][10] = aw0/denom[m]
//  P4 main    : 5*MCH units -> opart[mc][n][f]
//  P5 reduce  : 200 units -> out ([T,F,H,W] transpose)
// ---------------------------------------------------------------------------
template<int NCH, int MCH>
__global__ __launch_bounds__(256, 3) void fused_kernel(
    const float* __restrict__ x1, const float* __restrict__ x2,
    const float* __restrict__ aw,
    const float* __restrict__ w1, const float* __restrict__ b1,
    const float* __restrict__ w2, const float* __restrict__ b2,
    const float* __restrict__ w3, const float* __restrict__ b3,
    float* __restrict__ Q, float* __restrict__ K, float* __restrict__ V,
    float* __restrict__ dpart, float* __restrict__ opart,
    unsigned* __restrict__ bar,
    float* __restrict__ out)
{
    const int tid = threadIdx.x;
    const int nclen = N_TOK / NCH;
    const int mclen = N_TOK / MCH;

    __shared__ __align__(16) float sq[DTILE * FP];   // P2 staging
    __shared__ __align__(16) float sk[MTILE * FP];   // P4 staging
    __shared__ __align__(16) float sv[MTILE * FP];   // P4 staging

    // ---------------- P1: qkv pointwise conv ----------------
    for (int u = blockIdx.x; u < 600; u += GRID) {
        int arr = u / 200;                 // 0=Q, 1=K, 2=V
        int rem = u - arr * 200;
        int f   = rem / 20;
        int nbk = rem - f * 20;
        int n   = nbk * 256 + tid;
        int t = n >> 10, p = n & 1023;

        const float* x    = (arr == 1) ? x2 : x1;
        const float* w    = (arr == 0) ? w1 : (arr == 1) ? w2 : w3;
        const float* bias = (arr == 0) ? b1 : (arr == 1) ? b2 : b3;
        float*       dst  = (arr == 0) ? Q  : (arr == 1) ? K  : V;

        const float* xp = x + t * (C_IN * 1024) + p;
        const float* wr = w + f * C_IN;

        float acc = 0.f;
#pragma unroll
        for (int i = 0; i < 16; ++i) {
            float4 wv = ((const float4*)wr)[i];
            acc = fmaf(wv.x, xp[(4 * i + 0) * 1024], acc);
            acc = fmaf(wv.y, xp[(4 * i + 1) * 1024], acc);
            acc = fmaf(wv.z, xp[(4 * i + 2) * 1024], acc);
            acc = fmaf(wv.w, xp[(4 * i + 3) * 1024], acc);
        }
        dst[n * FP + f] = acc + bias[f];
    }
    grid_barrier(bar, 0, GRID);

    // ---------------- P2: partial softmax denominators ----------------
    for (int u = blockIdx.x; u < 5 * NCH; u += GRID) {
        int mTile = u % 5;
        int nc    = u / 5;
        int m0 = mTile * 1024 + tid;

        float kk[4][10];
#pragma unroll
        for (int c = 0; c < 4; ++c) {
            const float* kp = K + (m0 + c * 256) * FP;
            float4 a = ((const float4*)kp)[0];
            float4 b = ((const float4*)kp)[1];
            float2 e = ((const float2*)kp)[4];
            kk[c][0]=a.x; kk[c][1]=a.y; kk[c][2]=a.z; kk[c][3]=a.w;
            kk[c][4]=b.x; kk[c][5]=b.y; kk[c][6]=b.z; kk[c][7]=b.w;
            kk[c][8]=e.x; kk[c][9]=e.y;
        }

        float d[4] = {0.f, 0.f, 0.f, 0.f};
        int n0 = nc * nclen;
        for (int base = n0; base < n0 + nclen; base += DTILE) {
            __syncthreads();
            if (tid < DTILE * FP / 4)
                ((float4*)sq)[tid] = ((const float4*)(Q + base * FP))[tid];
            __syncthreads();
#pragma unroll 2
            for (int j = 0; j < DTILE; ++j) {
                const float4* qp = (const float4*)(sq + j * FP);
                float4 qa = qp[0], qb = qp[1], qc = qp[2];
                float qq[10] = {qa.x, qa.y, qa.z, qa.w, qb.x, qb.y, qb.z, qb.w,
                                qc.x, qc.y};
#pragma unroll
                for (int c = 0; c < 4; ++c) {
                    float s = 0.f;
#pragma unroll
                    for (int f = 0; f < F_OUT; ++f) s = fmaf(qq[f], kk[c][f], s);
                    d[c] += __expf(fminf(s, 60.f));
                }
            }
        }
#pragma unroll
        for (int c = 0; c < 4; ++c) dpart[nc * N_TOK + m0 + c * 256] = d[c];
    }
    grid_barrier(bar, 1, GRID);

    // ---------------- P3: invw into K row slot 10 ----------------
    for (int u = blockIdx.x; u < 20; u += GRID) {
        int m = u * 256 + tid;
        float d = 0.f;
#pragma unroll 8
        for (int c = 0; c < NCH; ++c) d += dpart[c * N_TOK + m];
        K[m * FP + 10] = aw[0] / d;
    }
    grid_barrier(bar, 2, GRID);

    // ---------------- P4: main fused pass ----------------
    // coef(n,m) = w0*relu(s) + w1*sigmoid(s) + exp(s)*invw[m]
    float w0 = aw[0], w1v = aw[1];
    for (int u = blockIdx.x; u < 5 * MCH; u += GRID) {
        int nTile = u % 5;
        int mc    = u / 5;
        int nb = nTile * 1024 + tid;

        float q[4][10];
#pragma unroll
        for (int r = 0; r < 4; ++r) {
            const float* qp = Q + (nb + r * 256) * FP;
            float4 a = ((const float4*)qp)[0];
            float4 b = ((const float4*)qp)[1];
            float2 e = ((const float2*)qp)[4];
            q[r][0]=a.x; q[r][1]=a.y; q[r][2]=a.z; q[r][3]=a.w;
            q[r][4]=b.x; q[r][5]=b.y; q[r][6]=b.z; q[r][7]=b.w;
            q[r][8]=e.x; q[r][9]=e.y;
        }

        float acc[4][F_OUT];
#pragma unroll
        for (int r = 0; r < 4; ++r)
#pragma unroll
            for (int f = 0; f < F_OUT; ++f) acc[r][f] = 0.f;

        int mstart = mc * mclen;
        for (int mbase = mstart; mbase < mstart + mclen; mbase += MTILE) {
            __syncthreads();
            if (tid < 120)
                ((float4*)sk)[tid] = ((const float4*)(K + mbase * FP))[tid];
            else if (tid < 240)
                ((float4*)sv)[tid - 120] = ((const float4*)(V + mbase * FP))[tid - 120];
            __syncthreads();

#pragma unroll 2
            for (int j = 0; j < MTILE; ++j) {
                const float4* kp = (const float4*)(sk + j * FP);
                float4 ka = kp[0], kb = kp[1], kc = kp[2];
                float kk[10] = {ka.x, ka.y, ka.z, ka.w, kb.x, kb.y, kb.z, kb.w,
                                kc.x, kc.y};
                float iw = kc.z;                     // invw packed at slot 10
                const float4* vp = (const float4*)(sv + j * FP);
                float4 va = vp[0], vb = vp[1], vc = vp[2];
                float vv[10] = {va.x, va.y, va.z, va.w, vb.x, vb.y, vb.z, vb.w,
                                vc.x, vc.y};

#pragma unroll
                for (int r = 0; r < 4; ++r) {
                    float s = 0.f;
#pragma unroll
                    for (int f = 0; f < F_OUT; ++f) s = fmaf(q[r][f], kk[f], s);
                    float rl = fmaxf(s, 0.f);
                    float e  = __expf(fminf(s, 60.f));
                    float sg = e * __builtin_amdgcn_rcpf(1.f + e);
                    float cf = fmaf(e, iw, fmaf(w1v, sg, w0 * rl));
#pragma unroll
                    for (int f = 0; f < F_OUT; ++f)
                        acc[r][f] = fmaf(cf, vv[f], acc[r][f]);
                }
            }
        }

#pragma unroll
        for (int r = 0; r < 4; ++r) {
            float2* o = (float2*)(opart + (size_t)(mc * N_TOK + nb + r * 256) * F_OUT);
#pragma unroll
            for (int f = 0; f < 5; ++f)
                o[f] = make_float2(acc[r][2 * f], acc[r][2 * f + 1]);
        }
    }
    grid_barrier(bar, 3, GRID);

    // ---------------- P5: reduce + transposed store ----------------
    for (int u = blockIdx.x; u < 200; u += GRID) {
        int idx = u * 256 + tid;
        float s = 0.f;
#pragma unroll 16
        for (int c = 0; c < MCH; ++c) s += opart[c * (N_TOK * F_OUT) + idx];
        unsigned un = (unsigned)idx / 10u;
        int n = (int)un;
        int f = idx - n * 10;
        int t = n >> 10, p = n & 1023;
        out[((t * F_OUT + f) << 10) + p] = s;
    }
}

// ---------------------------------------------------------------------------
extern "C" void kernel_launch(void* const* d_in, const int* in_sizes, int n_in,
                              void* d_out, int out_size, void* d_ws, size_t ws_size,
                              hipStream_t stream)
{
    const float* in1 = (const float*)d_in[0];
    const float* in2 = (const float*)d_in[1];
    const float* aw  = (const float*)d_in[2];
    const float* w1  = (const float*)d_in[3];
    const float* b1  = (const float*)d_in[4];
    const float* w2  = (const float*)d_in[5];
    const float* b2  = (const float*)d_in[6];
    const float* w3  = (const float*)d_in[7];
    const float* b3  = (const float*)d_in[8];
    float* out = (float*)d_out;

    float* ws = (float*)d_ws;
    float* Q  = ws;                         // N*FP
    float* K  = Q + N_TOK * FP;
    float* V  = K + N_TOK * FP;
    float* dpart = V + N_TOK * FP;          // NCH*N

    if (ws_size >= ((size_t)32 << 20)) {
        float* opart = dpart + 128 * N_TOK;            // 128*N*10
        unsigned* bar = (unsigned*)(opart + (size_t)128 * N_TOK * F_OUT);
        hipMemsetAsync(bar, 0, 4 * 16 * sizeof(unsigned), stream);
        fused_kernel<128, 128><<<GRID, 256, 0, stream>>>(
            in1, in2, aw, w1, b1, w2, b2, w3, b3,
            Q, K, V, dpart, opart, bar, out);
    } else {
        float* opart = dpart + 32 * N_TOK;             // 32*N*10
        unsigned* bar = (unsigned*)(opart + (size_t)32 * N_TOK * F_OUT);
        hipMemsetAsync(bar, 0, 4 * 16 * sizeof(unsigned), stream);
        fused_kernel<32, 32><<<GRID, 256, 0, stream>>>(
            in1, in2, aw, w1, b1, w2, b2, w3, b3,
            Q, K, V, dpart, opart, bar, out);
    }
}

// Round 7
// 139.941 us; speedup vs baseline: 4.8080x; 4.8080x over previous
//
#include <hip/hip_runtime.h>

// Problem constants: B=1, T=5, C=64, H=W=32, F=10
#define N_TOK   5120      // T*H*W
#define C_IN    64
#define F_OUT   10
#define FP      12        // padded row stride (3 x float4); slots 10,11 junk
#define DTILE   20        // denom: Q rows per LDS tile
#define MTILE   20        // main: K/V rows per LDS tile

// ---------------------------------------------------------------------------
// Kernel A: q/k/v pointwise conv. Thread = one (n, f, arr) output value.
// 600 blocks: arr(3) x f(10) x nblk(20). 64 independent coalesced loads.
// ---------------------------------------------------------------------------
__global__ __launch_bounds__(256) void qkv_kernel(
    const float* __restrict__ x1, const float* __restrict__ x2,
    const float* __restrict__ w1, const float* __restrict__ b1,
    const float* __restrict__ w2, const float* __restrict__ b2,
    const float* __restrict__ w3, const float* __restrict__ b3,
    float* __restrict__ Q, float* __restrict__ K, float* __restrict__ V)
{
    int arr = blockIdx.x / 200;            // 0=Q, 1=K, 2=V
    int rem = blockIdx.x - arr * 200;
    int f   = rem / 20;
    int nbk = rem - f * 20;
    int n   = nbk * 256 + threadIdx.x;
    int t = n >> 10, p = n & 1023;

    const float* x    = (arr == 1) ? x2 : x1;
    const float* w    = (arr == 0) ? w1 : (arr == 1) ? w2 : w3;
    const float* bias = (arr == 0) ? b1 : (arr == 1) ? b2 : b3;
    float*       dst  = (arr == 0) ? Q  : (arr == 1) ? K  : V;

    const float* xp = x + t * (C_IN * 1024) + p;
    const float* wr = w + f * C_IN;

    float acc = 0.f;
#pragma unroll
    for (int i = 0; i < 16; ++i) {
        float4 wv = ((const float4*)wr)[i];
        acc = fmaf(wv.x, xp[(4 * i + 0) * 1024], acc);
        acc = fmaf(wv.y, xp[(4 * i + 1) * 1024], acc);
        acc = fmaf(wv.z, xp[(4 * i + 2) * 1024], acc);
        acc = fmaf(wv.w, xp[(4 * i + 3) * 1024], acc);
    }
    dst[n * FP + f] = acc + bias[f];
}

// ---------------------------------------------------------------------------
// Kernel B: partial softmax denominators. Thread owns FOUR m-columns (K in
// regs); Q rows staged via small LDS tiles. Grid = 5 mTiles x NCH (big: 1280
// blocks = 5 blocks/CU -> latency hidden across blocks).
// ---------------------------------------------------------------------------
template<int NCH>
__global__ __launch_bounds__(256, 4) void denom_kernel(
    const float* __restrict__ Q, const float* __restrict__ K,
    float* __restrict__ dpart)
{
    const int nclen = N_TOK / NCH;
    int mTile = blockIdx.x % 5;
    int nc    = blockIdx.x / 5;
    int tid   = threadIdx.x;
    int m0 = mTile * 1024 + tid;

    float kk[4][10];
#pragma unroll
    for (int c = 0; c < 4; ++c) {
        const float* kp = K + (m0 + c * 256) * FP;
        float4 a = ((const float4*)kp)[0];
        float4 b = ((const float4*)kp)[1];
        float2 e = ((const float2*)kp)[4];
        kk[c][0]=a.x; kk[c][1]=a.y; kk[c][2]=a.z; kk[c][3]=a.w;
        kk[c][4]=b.x; kk[c][5]=b.y; kk[c][6]=b.z; kk[c][7]=b.w;
        kk[c][8]=e.x; kk[c][9]=e.y;
    }

    __shared__ __align__(16) float sq[DTILE * FP];   // 240 floats

    float d[4] = {0.f, 0.f, 0.f, 0.f};
    int n0 = nc * nclen;
    for (int base = n0; base < n0 + nclen; base += DTILE) {
        __syncthreads();
        if (tid < DTILE * FP / 4)   // 60 coalesced float4 loads
            ((float4*)sq)[tid] = ((const float4*)(Q + base * FP))[tid];
        __syncthreads();
#pragma unroll 2
        for (int j = 0; j < DTILE; ++j) {
            const float4* qp = (const float4*)(sq + j * FP);
            float4 qa = qp[0], qb = qp[1], qc = qp[2];
            float qq[10] = {qa.x, qa.y, qa.z, qa.w, qb.x, qb.y, qb.z, qb.w,
                            qc.x, qc.y};
#pragma unroll
            for (int c = 0; c < 4; ++c) {
                float s = 0.f;
#pragma unroll
                for (int f = 0; f < F_OUT; ++f) s = fmaf(qq[f], kk[c][f], s);
                d[c] += __expf(fminf(s, 60.f));
            }
        }
    }
#pragma unroll
    for (int c = 0; c < 4; ++c) dpart[nc * N_TOK + m0 + c * 256] = d[c];
}

// ---------------------------------------------------------------------------
// Kernel C: main fused pass with BLOCK-LOCAL invw (kills the invw launch).
// Grid = 5 nTiles x MCH (big: 640 blocks). Thread owns 4 rows n; K/V staged
// via LDS tiles of MTILE; invw for this block's mclen columns summed from
// dpart into LDS up front.
// coef(n,m) = w0*relu(s) + w1*sigmoid(s) + exp(s)*invw[m]
// ---------------------------------------------------------------------------
template<int NCH, int MCH>
__global__ __launch_bounds__(256, 4) void main_kernel(
    const float* __restrict__ Q, const float* __restrict__ K,
    const float* __restrict__ V, const float* __restrict__ dpart,
    const float* __restrict__ aw, float* __restrict__ opart)
{
    const int mclen = N_TOK / MCH;
    int nTile = blockIdx.x % 5;
    int mc    = blockIdx.x / 5;
    int tid   = threadIdx.x;
    int nb = nTile * 1024 + tid;
    int mstart = mc * mclen;
    float w0 = aw[0], w1v = aw[1];

    __shared__ __align__(16) float sk[MTILE * FP];
    __shared__ __align__(16) float sv[MTILE * FP];
    __shared__ float siw[320];                       // covers mclen <= 320

    // block-local invw: siw[t] = w0 / sum_c dpart[c][mstart+t]
    for (int t = tid; t < mclen; t += 256) {
        float d = 0.f;
#pragma unroll 8
        for (int c = 0; c < NCH; ++c) d += dpart[c * N_TOK + mstart + t];
        siw[t] = w0 / d;
    }
    // (ordered before first use by the staging __syncthreads below)

    float q[4][10];
#pragma unroll
    for (int r = 0; r < 4; ++r) {
        const float* qp = Q + (nb + r * 256) * FP;
        float4 a = ((const float4*)qp)[0];
        float4 b = ((const float4*)qp)[1];
        float2 e = ((const float2*)qp)[4];
        q[r][0]=a.x; q[r][1]=a.y; q[r][2]=a.z; q[r][3]=a.w;
        q[r][4]=b.x; q[r][5]=b.y; q[r][6]=b.z; q[r][7]=b.w;
        q[r][8]=e.x; q[r][9]=e.y;
    }

    float acc[4][F_OUT];
#pragma unroll
    for (int r = 0; r < 4; ++r)
#pragma unroll
        for (int f = 0; f < F_OUT; ++f) acc[r][f] = 0.f;

    for (int mbase = mstart; mbase < mstart + mclen; mbase += MTILE) {
        __syncthreads();
        if (tid < 60)
            ((float4*)sk)[tid] = ((const float4*)(K + mbase * FP))[tid];
        else if (tid < 120)
            ((float4*)sv)[tid - 60] = ((const float4*)(V + mbase * FP))[tid - 60];
        __syncthreads();

#pragma unroll 2
        for (int j = 0; j < MTILE; ++j) {
            const float4* kp = (const float4*)(sk + j * FP);
            float4 ka = kp[0], kb = kp[1], kc = kp[2];
            float kk[10] = {ka.x, ka.y, ka.z, ka.w, kb.x, kb.y, kb.z, kb.w,
                            kc.x, kc.y};
            const float4* vp = (const float4*)(sv + j * FP);
            float4 va = vp[0], vb = vp[1], vc = vp[2];
            float vv[10] = {va.x, va.y, va.z, va.w, vb.x, vb.y, vb.z, vb.w,
                            vc.x, vc.y};
            float iw = siw[mbase - mstart + j];

#pragma unroll
            for (int r = 0; r < 4; ++r) {
                float s = 0.f;
#pragma unroll
                for (int f = 0; f < F_OUT; ++f) s = fmaf(q[r][f], kk[f], s);
                float rl = fmaxf(s, 0.f);
                float e  = __expf(fminf(s, 60.f));
                float sg = e * __builtin_amdgcn_rcpf(1.f + e);
                float cf = fmaf(e, iw, fmaf(w1v, sg, w0 * rl));
#pragma unroll
                for (int f = 0; f < F_OUT; ++f)
                    acc[r][f] = fmaf(cf, vv[f], acc[r][f]);
            }
        }
    }

#pragma unroll
    for (int r = 0; r < 4; ++r) {
        float2* o = (float2*)(opart + (size_t)(mc * N_TOK + nb + r * 256) * F_OUT);
#pragma unroll
        for (int f = 0; f < 5; ++f)
            o[f] = make_float2(acc[r][2 * f], acc[r][2 * f + 1]);
    }
}

// ---------------------------------------------------------------------------
// Kernel D: reduce m-chunk partials; write with [T,F,H,W] transpose
// ---------------------------------------------------------------------------
template<int MCH>
__global__ __launch_bounds__(256) void reduce_kernel(
    const float* __restrict__ opart, float* __restrict__ out)
{
    int idx = blockIdx.x * 256 + threadIdx.x;    // 200 blocks * 256 = 51200
    float s = 0.f;
#pragma unroll 16
    for (int c = 0; c < MCH; ++c) s += opart[c * (N_TOK * F_OUT) + idx];
    unsigned un = (unsigned)idx / 10u;
    int n = (int)un;
    int f = idx - n * 10;
    int t = n >> 10, p = n & 1023;
    out[((t * F_OUT + f) << 10) + p] = s;
}

// ---------------------------------------------------------------------------
template<int NCH, int MCH>
static void run_all(const float* in1, const float* in2, const float* aw,
                    const float* w1, const float* b1,
                    const float* w2, const float* b2,
                    const float* w3, const float* b3,
                    float* out, float* ws, hipStream_t stream)
{
    float* Q     = ws;                        // N*FP
    float* K     = Q + N_TOK * FP;
    float* V     = K + N_TOK * FP;
    float* dpart = V + N_TOK * FP;            // NCH*N
    float* opart = dpart + NCH * N_TOK;       // MCH*N*10

    qkv_kernel<<<600, 256, 0, stream>>>(in1, in2, w1, b1, w2, b2, w3, b3, Q, K, V);
    denom_kernel<NCH><<<5 * NCH, 256, 0, stream>>>(Q, K, dpart);
    main_kernel<NCH, MCH><<<5 * MCH, 256, 0, stream>>>(Q, K, V, dpart, aw, opart);
    reduce_kernel<MCH><<<(N_TOK * F_OUT) / 256, 256, 0, stream>>>(opart, out);
}

extern "C" void kernel_launch(void* const* d_in, const int* in_sizes, int n_in,
                              void* d_out, int out_size, void* d_ws, size_t ws_size,
                              hipStream_t stream)
{
    const float* in1 = (const float*)d_in[0];
    const float* in2 = (const float*)d_in[1];
    const float* aw  = (const float*)d_in[2];
    const float* w1  = (const float*)d_in[3];
    const float* b1  = (const float*)d_in[4];
    const float* w2  = (const float*)d_in[5];
    const float* b2  = (const float*)d_in[6];
    const float* w3  = (const float*)d_in[7];
    const float* b3  = (const float*)d_in[8];
    float* out = (float*)d_out;
    float* ws  = (float*)d_ws;

    if (ws_size >= ((size_t)48 << 20))        // 32.2 MB used
        run_all<256, 128>(in1, in2, aw, w1, b1, w2, b2, w3, b3, out, ws, stream);
    else if (ws_size >= ((size_t)16 << 20))   // 15.2 MB used
        run_all<64, 64>(in1, in2, aw, w1, b1, w2, b2, w3, b3, out, ws, stream);
    else                                      // 4.4 MB used
        run_all<16, 16>(in1, in2, aw, w1, b1, w2, b2, w3, b3, out, ws, stream);
}